// Round 3
// baseline (318.110 us; speedup 1.0000x reference)
//
#include <hip/hip_runtime.h>
#include <hip/hip_fp16.h>

// GCN 2-layer, CSR-gather formulation, fp16 storage / fp32 math, MFMA GEMMs.
//   y = half(x * dinv)                          [fused into k_fillb]
//   per 64-row block (k_fused, one wave per 16 rows, no barriers):
//     aggX = dinv[c] * (y[c] + sum y[r])   -> wave-private LDS
//     h1   = relu(aggX @ W1 + b1)          -> same LDS buffer    [MFMA f16]
//     z    = (h1 @ W2) * dinv              -> global (64-wide)   [MFMA f16]
//   out[c] = fp32( dinv[c] * (z[c] + sum z[r]) + b2 )            [k_gath2]
// CSR build is fully deterministic, no global atomics (see R1-R7 lessons).
//
// R2 lesson: random-gather BW scales linearly with occupancy (k_gath1:
// 74% occ -> 3.55 TB/s; fused w/ 34.8KB LDS: 32% occ -> 1.93 TB/s; both
// ratios 0.43). R3 (this round): single LDS buffer (17.4 KB) -- preload
// A-fragments to VGPRs before each MFMA stage, then overwrite the buffer
// with that stage's output (wave-private, in-order DS pipe). launch_bounds
// (256,6) pins >=6 waves/SIMD. Target: restore 70%+ occ in k_fused.

constexpr int NN = 100000;   // nodes
constexpr int NE = 1600000;  // edges
constexpr int BSH = 7;       // 128 nodes per bucket
constexpr int NB = (NN + 127) >> BSH;  // 782 buckets
constexpr int NBLK = 256;    // binning blocks
constexpr int EPB = NE / NBLK;  // 6250 edges per block (exact)
constexpr int TSTR = 784;    // table row stride (ints)

typedef _Float16 f16x8 __attribute__((ext_vector_type(8)));
typedef float f32x4 __attribute__((ext_vector_type(4)));

// ------------- per-(block,bucket) histogram (LDS atomics only) ---------------
__global__ __launch_bounds__(256) void k_hist(const int* __restrict__ cols,
                                              int* __restrict__ table) {
  __shared__ int cnt[NB];
  for (int i = threadIdx.x; i < NB; i += 256) cnt[i] = 0;
  __syncthreads();
  int base = blockIdx.x * EPB;
  for (int i = threadIdx.x; i < EPB; i += 256)
    atomicAdd(&cnt[cols[base + i] >> BSH], 1);
  __syncthreads();
  for (int i = threadIdx.x; i < NB; i += 256)
    table[blockIdx.x * TSTR + i] = cnt[i];
}

// ------- scan table columns over blocks: startOff + bucket totals ------------
__global__ __launch_bounds__(256) void k_scanT(const int* __restrict__ table,
                                               int* __restrict__ startOff,
                                               int* __restrict__ btot) {
  __shared__ int s[256];
  int b = blockIdx.x, t = threadIdx.x;
  int v = table[t * TSTR + b];
  s[t] = v;
  __syncthreads();
  for (int off = 1; off < 256; off <<= 1) {
    int tmp = (t >= off) ? s[t - off] : 0;
    __syncthreads();
    s[t] += tmp;
    __syncthreads();
  }
  startOff[t * TSTR + b] = s[t] - v;
  if (t == 255) btot[b] = s[t];
}

// ------- exclusive scan of 782 bucket totals -> bucketBase (1 block) ---------
__global__ __launch_bounds__(256) void k_scanBkt(const int* __restrict__ btot,
                                                 int* __restrict__ bucketBase) {
  __shared__ int s[256];
  int t = threadIdx.x;
  int base = t * 4;
  int d0 = (base + 0 < NB) ? btot[base + 0] : 0;
  int d1 = (base + 1 < NB) ? btot[base + 1] : 0;
  int d2 = (base + 2 < NB) ? btot[base + 2] : 0;
  int d3 = (base + 3 < NB) ? btot[base + 3] : 0;
  int tsum = d0 + d1 + d2 + d3;
  s[t] = tsum;
  __syncthreads();
  for (int off = 1; off < 256; off <<= 1) {
    int tmp = (t >= off) ? s[t - off] : 0;
    __syncthreads();
    s[t] += tmp;
    __syncthreads();
  }
  int ex = s[t] - tsum;
  if (base + 0 < NB) bucketBase[base + 0] = ex;
  if (base + 1 < NB) bucketBase[base + 1] = ex + d0;
  if (base + 2 < NB) bucketBase[base + 2] = ex + d0 + d1;
  if (base + 3 < NB) bucketBase[base + 3] = ex + d0 + d1 + d2;
}

// ------- scatter edges into bucket-grouped array (LDS counters only) ---------
__global__ __launch_bounds__(256) void k_scat(const int* __restrict__ rows,
                                              const int* __restrict__ cols,
                                              const int* __restrict__ startOff,
                                              const int* __restrict__ bucketBase,
                                              unsigned* __restrict__ binned) {
  __shared__ int scnt[NB];
  int blk = blockIdx.x;
  for (int i = threadIdx.x; i < NB; i += 256)
    scnt[i] = bucketBase[i] + startOff[blk * TSTR + i];
  __syncthreads();
  int base = blk * EPB;
  for (int i = threadIdx.x; i < EPB; i += 256) {
    int c = cols[base + i];
    int r = rows[base + i];
    int pos = atomicAdd(&scnt[c >> BSH], 1);
    binned[pos] = ((unsigned)r << BSH) | (unsigned)(c & 127);
  }
}

// ------- per-bucket fill: deg/rowptr/dinv + node-grouped srcIdx + y ----------
// one block per bucket; block exclusively owns all its output ranges.
// also converts this bucket's x rows to y = half(x*dinv) (k_y fused).
__global__ __launch_bounds__(256) void k_fillb(const unsigned* __restrict__ binned,
                                               const int* __restrict__ bucketBase,
                                               const int* __restrict__ btot,
                                               int* __restrict__ rowptr,
                                               int* __restrict__ deg,
                                               float* __restrict__ dinv,
                                               int* __restrict__ srcIdx,
                                               const float4* __restrict__ x4,
                                               float2* __restrict__ y8) {
  __shared__ int cnt[128];
  __shared__ int sc[128];
  __shared__ int rp[128];
  __shared__ float sdv[128];
  int b = blockIdx.x;
  int nb0 = b << BSH;
  int nn = min(128, NN - nb0);
  int tid = threadIdx.x;
  if (tid < 128) cnt[tid] = 0;
  __syncthreads();
  int ebeg = bucketBase[b];
  int eend = ebeg + btot[b];
  // pass 1: local degree count
  for (int p = ebeg + tid; p < eend; p += 256)
    atomicAdd(&cnt[binned[p] & 127], 1);
  __syncthreads();
  // block scan of the 128 local degrees
  int v = (tid < 128) ? cnt[tid] : 0;
  if (tid < 128) sc[tid] = v;
  __syncthreads();
  for (int off = 1; off < 128; off <<= 1) {
    int tmp = (tid < 128 && tid >= off) ? sc[tid - off] : 0;
    __syncthreads();
    if (tid < 128) sc[tid] += tmp;
    __syncthreads();
  }
  if (tid < 128) {
    int ex = sc[tid] - v;
    rp[tid] = ebeg + ex;
    float dv = rsqrtf((float)v + 1.0f);
    sdv[tid] = dv;
    if (tid < nn) {
      rowptr[nb0 + tid] = ebeg + ex;
      deg[nb0 + tid] = v;
      dinv[nb0 + tid] = dv;
    }
    cnt[tid] = 0;
  }
  __syncthreads();
  // pass 2: scatter srcIdx (node-grouped, contiguous per bucket)
  for (int p = ebeg + tid; p < eend; p += 256) {
    unsigned pk = binned[p];
    int cl = pk & 127;
    int local = atomicAdd(&cnt[cl], 1);
    srcIdx[rp[cl] + local] = (int)(pk >> BSH);
  }
  // pass 3 (fused k_y): convert this bucket's x rows -> y = half(x*dinv)
  int tot = nn << 5;  // nn rows * 32 float4 each
  const float4* xb = x4 + ((size_t)nb0 << 5);
  float2* yb = y8 + ((size_t)nb0 << 5);
  for (int i = tid; i < tot; i += 256) {
    float s = sdv[i >> 5];
    float4 vv = xb[i];
    union { __half2 h[2]; float2 f; } u;
    u.h[0] = __floats2half2_rn(vv.x * s, vv.y * s);
    u.h[1] = __floats2half2_rn(vv.z * s, vv.w * s);
    yb[i] = u.f;
  }
}

// ------------- weight convert+transpose, both layers in one launch ----------
// W1 [128][128] -> Wt1 [128][128]^T, W2 [128][64] -> Wt2 [64][128]^T (f16)
__global__ __launch_bounds__(256) void k_wt(const float* __restrict__ W1,
                                            const float* __restrict__ W2,
                                            __half* __restrict__ Wt1,
                                            __half* __restrict__ Wt2) {
  int i = blockIdx.x * 256 + threadIdx.x;  // 96*256 = 24576 = 16384 + 8192
  if (i < 16384) {
    int k = i >> 7, n = i & 127;
    Wt1[n * 128 + k] = __float2half(W1[i]);
  } else {
    int j = i - 16384;
    int k = j >> 6, n = j & 63;
    Wt2[n * 128 + k] = __float2half(W2[j]);
  }
}

// ---- fused gather + GEMM1(+bias,relu) + GEMM2(+dinv) ------------------------
// block = 64 rows, 4 waves, wave owns rows [rowTop, rowTop+16). Everything is
// wave-private through ONE 4.3KB-per-wave LDS buffer -> ZERO __syncthreads.
// Stage hazard handling: before each MFMA stage, preload this lane's 4
// A-fragments (16 VGPR) from the buffer; the stage output then overwrites the
// same buffer (in-order DS pipe + compiler lgkmcnt ordering, wave-private).
// Gather: 4 slots x 16 lanes (16 lanes = one 256B row), 2-deep unroll.
// MFMA 16x16x32 f16, fp32 acc. C/D: lane reg i = C[(l>>4)*4+i][t*16+(l&15)].
__global__ __launch_bounds__(256, 6) void k_fused(
    const __half* __restrict__ y, const int* __restrict__ rowptr,
    const int* __restrict__ deg, const int* __restrict__ srcIdx,
    const float* __restrict__ dinv, const __half* __restrict__ Wt1,
    const float* __restrict__ b1, const __half* __restrict__ Wt2,
    __half* __restrict__ z) {
  __shared__ __align__(16) __half sA[4][16][136];  // aggX -> h1 -> z staging
  const int w = threadIdx.x >> 6, l = threadIdx.x & 63;
  const int rowTop = blockIdx.x * 64 + w * 16;
  if (rowTop >= NN) return;  // NN%16==0: whole wave valid or invalid
  const int quad = l >> 4, m = l & 15;  // slot / in-slot lane
  const int sb = l & 48;                // slot base lane

  // ---------------- gather phase: 4 passes x 4 slot-nodes ----------------
  for (int p = 0; p < 4; ++p) {
    int node = rowTop + p * 4 + quad;
    int d = deg[node];
    int ptr = rowptr[node];
    float acc[8];
#pragma unroll
    for (int i = 0; i < 8; i++) acc[i] = 0.0f;
    for (int base = 0; base < d; base += 16) {
      int cntv = min(16, d - base);
      int my = (m < cntv) ? srcIdx[ptr + base + m] : 0;
      int k = 0;
      for (; k + 2 <= cntv; k += 2) {
        int s0 = __shfl(my, sb + k);
        int s1 = __shfl(my, sb + k + 1);
        f16x8 v0 = *reinterpret_cast<const f16x8*>(y + (size_t)s0 * 128 + m * 8);
        f16x8 v1 = *reinterpret_cast<const f16x8*>(y + (size_t)s1 * 128 + m * 8);
#pragma unroll
        for (int i = 0; i < 8; i++) acc[i] += (float)v0[i];
#pragma unroll
        for (int i = 0; i < 8; i++) acc[i] += (float)v1[i];
      }
      if (k < cntv) {
        int s0 = __shfl(my, sb + k);
        f16x8 v0 = *reinterpret_cast<const f16x8*>(y + (size_t)s0 * 128 + m * 8);
#pragma unroll
        for (int i = 0; i < 8; i++) acc[i] += (float)v0[i];
      }
    }
    f16x8 sv = *reinterpret_cast<const f16x8*>(y + (size_t)node * 128 + m * 8);
    float scn = dinv[node];
    f16x8 o;
#pragma unroll
    for (int i = 0; i < 8; i++) o[i] = (_Float16)((acc[i] + (float)sv[i]) * scn);
    *reinterpret_cast<f16x8*>(&sA[w][p * 4 + quad][m * 8]) = o;
  }

  // ---------------- GEMM1: h1 = relu(aggX @ W1 + b1) ----------------
  f16x8 afrag[4];
#pragma unroll
  for (int kk = 0; kk < 4; kk++)
    afrag[kk] = *reinterpret_cast<const f16x8*>(&sA[w][m][kk * 32 + quad * 8]);
  f32x4 acc1[8];
#pragma unroll
  for (int t = 0; t < 8; t++) {
    float bv = b1[t * 16 + m];
    acc1[t] = (f32x4){bv, bv, bv, bv};
  }
#pragma unroll
  for (int kk = 0; kk < 4; kk++) {
#pragma unroll
    for (int t = 0; t < 8; t++) {
      f16x8 b = *reinterpret_cast<const f16x8*>(
          Wt1 + (size_t)(t * 16 + m) * 128 + kk * 32 + quad * 8);
      acc1[t] = __builtin_amdgcn_mfma_f32_16x16x32_f16(afrag[kk], b, acc1[t], 0, 0, 0);
    }
  }
  // overwrite sA with h1 (afrag already in VGPRs; MFMA consumed them)
#pragma unroll
  for (int t = 0; t < 8; t++)
#pragma unroll
    for (int i = 0; i < 4; i++)
      sA[w][quad * 4 + i][t * 16 + m] = __float2half(fmaxf(acc1[t][i], 0.0f));

  // ---------------- GEMM2: z = (h1 @ W2) * dinv[row] ----------------
  f16x8 hfrag[4];
#pragma unroll
  for (int kk = 0; kk < 4; kk++)
    hfrag[kk] = *reinterpret_cast<const f16x8*>(&sA[w][m][kk * 32 + quad * 8]);
  f32x4 acc2[4];
#pragma unroll
  for (int t = 0; t < 4; t++) acc2[t] = (f32x4){0.f, 0.f, 0.f, 0.f};
#pragma unroll
  for (int kk = 0; kk < 4; kk++) {
#pragma unroll
    for (int t = 0; t < 4; t++) {
      f16x8 b = *reinterpret_cast<const f16x8*>(
          Wt2 + (size_t)(t * 16 + m) * 128 + kk * 32 + quad * 8);
      acc2[t] = __builtin_amdgcn_mfma_f32_16x16x32_f16(hfrag[kk], b, acc2[t], 0, 0, 0);
    }
  }
  float rs[4];
#pragma unroll
  for (int i = 0; i < 4; i++) rs[i] = dinv[rowTop + quad * 4 + i];
  // overwrite sA with z tile (hfrag in VGPRs)
#pragma unroll
  for (int t = 0; t < 4; t++)
#pragma unroll
    for (int i = 0; i < 4; i++)
      sA[w][quad * 4 + i][t * 16 + m] = __float2half(acc2[t][i] * rs[i]);

  // vectorized store: 16 rows x 64 halves (128B/row)
#pragma unroll
  for (int rep = 0; rep < 2; rep++) {
    int idx = rep * 64 + l;
    int r = idx >> 3, cc = idx & 7;
    *reinterpret_cast<float4*>(z + (size_t)(rowTop + r) * 64 + cc * 8) =
        *reinterpret_cast<const float4*>(&sA[w][r][cc * 8]);
  }
}

// ---------------- gather-aggregate, width 64 half (wave per node) ------------
// 16B/lane: 8 lanes cover one 128B source row -> 8 neighbor rows per load
// instruction, 2-deep unroll = 16 rows in flight. Butterfly xor 8/16/32.
__global__ __launch_bounds__(256) void k_gath2(const __half* __restrict__ z,
                                               const int* __restrict__ rowptr,
                                               const int* __restrict__ deg,
                                               const int* __restrict__ srcIdx,
                                               const float* __restrict__ dinv,
                                               const float* __restrict__ b2,
                                               float* __restrict__ out) {
  int node = blockIdx.x * 4 + (threadIdx.x >> 6);
  if (node >= NN) return;
  int lane = threadIdx.x & 63;
  int g = lane >> 3;       // neighbor slot 0..7
  int c = lane & 7;        // column chunk: halfs [c*8, c*8+8)
  int d = deg[node];
  int p = rowptr[node];
  size_t coff = (size_t)c * 8;
  float acc[8];
#pragma unroll
  for (int i = 0; i < 8; i++) acc[i] = 0.0f;

  for (int base = 0; base < d; base += 64) {
    int cnt = min(64, d - base);
    int my = (lane < cnt) ? srcIdx[p + base + lane] : 0;
    int k = 0;
    for (; k + 16 <= cnt; k += 16) {         // 16 neighbors, 2 loads in flight
      int s0 = __shfl(my, k + g);
      int s1 = __shfl(my, k + 8 + g);
      f16x8 v0 = *reinterpret_cast<const f16x8*>(z + (size_t)s0 * 64 + coff);
      f16x8 v1 = *reinterpret_cast<const f16x8*>(z + (size_t)s1 * 64 + coff);
#pragma unroll
      for (int i = 0; i < 8; i++) acc[i] += (float)v0[i];
#pragma unroll
      for (int i = 0; i < 8; i++) acc[i] += (float)v1[i];
    }
    for (; k < cnt; k += 8) {                // remainder, predicated
      int idx = k + g;
      bool valid = idx < cnt;
      int s0 = __shfl(my, valid ? idx : 0);
      f16x8 v0 = *reinterpret_cast<const f16x8*>(z + (size_t)s0 * 64 + coff);
      if (valid) {
#pragma unroll
        for (int i = 0; i < 8; i++) acc[i] += (float)v0[i];
      }
    }
  }
#pragma unroll
  for (int i = 0; i < 8; i++) acc[i] += __shfl_xor(acc[i], 8);
#pragma unroll
  for (int i = 0; i < 8; i++) acc[i] += __shfl_xor(acc[i], 16);
#pragma unroll
  for (int i = 0; i < 8; i++) acc[i] += __shfl_xor(acc[i], 32);
  if (g == 0) {
    f16x8 sv = *reinterpret_cast<const f16x8*>(z + (size_t)node * 64 + coff);
    float s = dinv[node];
    const float4* b4 = reinterpret_cast<const float4*>(b2);
    float4 bv0 = b4[2 * c], bv1 = b4[2 * c + 1];
    float4 o0, o1;
    o0.x = (acc[0] + (float)sv[0]) * s + bv0.x;
    o0.y = (acc[1] + (float)sv[1]) * s + bv0.y;
    o0.z = (acc[2] + (float)sv[2]) * s + bv0.z;
    o0.w = (acc[3] + (float)sv[3]) * s + bv0.w;
    o1.x = (acc[4] + (float)sv[4]) * s + bv1.x;
    o1.y = (acc[5] + (float)sv[5]) * s + bv1.y;
    o1.z = (acc[6] + (float)sv[6]) * s + bv1.z;
    o1.w = (acc[7] + (float)sv[7]) * s + bv1.w;
    float4* op = reinterpret_cast<float4*>(out + (size_t)node * 64 + coff);
    op[0] = o0;
    op[1] = o1;
  }
}

extern "C" void kernel_launch(void* const* d_in, const int* in_sizes, int n_in,
                              void* d_out, int out_size, void* d_ws, size_t ws_size,
                              hipStream_t stream) {
  const float* x  = (const float*)d_in[0];
  const int*   ei = (const int*)d_in[1];  // [2, NE] row-major
  const int* rows = ei;
  const int* cols = ei + NE;
  const float* W1 = (const float*)d_in[3];
  const float* b1 = (const float*)d_in[4];
  const float* W2 = (const float*)d_in[5];
  const float* b2 = (const float*)d_in[6];
  float* out = (float*)d_out;

  // ---- workspace carve (~60 MB) ----
  char* base = (char*)d_ws;
  constexpr size_t MB = 1 << 20;
  int*      deg       = (int*)(base + 0 * MB);
  int*      rowptr    = (int*)(base + 1 * MB);
  float*    dinv      = (float*)(base + 2 * MB);
  int*      btot      = (int*)(base + 3 * MB);                  // 3.2 KB
  int*      bucketBase= (int*)(base + 3 * MB + 16 * 1024);      // 3.2 KB
  __half*   Wt1       = (__half*)(base + 3 * MB + 64 * 1024);   // 32 KB
  __half*   Wt2       = (__half*)(base + 3 * MB + 128 * 1024);  // 16 KB
  int*      table     = (int*)(base + 4 * MB);   // 803 KB
  int*      startOff  = (int*)(base + 5 * MB);   // 803 KB
  unsigned* binned    = (unsigned*)(base + 6 * MB);   // 6.4 MB
  int*      srcIdx    = (int*)(base + 13 * MB);       // 6.4 MB
  __half*   y         = (__half*)(base + 20 * MB);    // 25.6 MB
  __half*   z         = (__half*)(base + 46 * MB);    // 12.8 MB (y stays live!)

  k_wt<<<96, 256, 0, stream>>>(W1, W2, Wt1, Wt2);
  k_hist<<<NBLK, 256, 0, stream>>>(cols, table);
  k_scanT<<<NB, 256, 0, stream>>>(table, startOff, btot);
  k_scanBkt<<<1, 256, 0, stream>>>(btot, bucketBase);
  k_scat<<<NBLK, 256, 0, stream>>>(rows, cols, startOff, bucketBase, binned);
  k_fillb<<<NB, 256, 0, stream>>>(binned, bucketBase, btot, rowptr, deg, dinv,
                                  srcIdx, (const float4*)x, (float2*)y);
  k_fused<<<(NN + 63) / 64, 256, 0, stream>>>(y, rowptr, deg, srcIdx, dinv,
                                              Wt1, b1, Wt2, z);
  k_gath2<<<(NN + 3) / 4, 256, 0, stream>>>(z, rowptr, deg, srcIdx, dinv, b2, out);
}

// Round 4
// 295.924 us; speedup vs baseline: 1.0750x; 1.0750x over previous
//
#include <hip/hip_runtime.h>
#include <hip/hip_fp16.h>

// GCN 2-layer, CSR-gather formulation, fp16 storage / fp32 math, MFMA GEMMs.
//   y = half(x * dinv)                          [fused into k_fillb]
//   k_fused (block = 32 rows, 4 waves, 3 barriers):
//     gather: each wave owns 8 rows, whole-wave-per-node loop (k_gath1's
//             proven wave-uniform structure, 8 rows in flight) -> sA
//     GEMM1:  relu(aggX @ W1 + b1), all 4 waves (rowhalf x colhalf) -> sB
//     GEMM2:  (h1 @ W2) * dinv, all 4 waves -> sA (dead after GEMM1 reads)
//     store:  32x64 f16 rows, vectorized
//   out[c] = fp32( dinv[c] * (z[c] + sum z[r]) + b2 )            [k_gath2]
// CSR build is fully deterministic, no global atomics (see R1-R7 lessons).
//
// R3 lesson: occupancy 32->49% moved BW not at all (1.93->1.90 TB/s).
// Deficits: (a) quad-divergent gather (4 nodes/wave, E[max d] ~ 22 vs
// E[d]=16, masked loads) cost ~20% per-wave efficiency vs k_gath1's
// wave-uniform loop; (b) wave-owns-16-rows caps total waves at NN/16 =
// 24.4/CU = 76%. R4: wave gathers 8 rows (NN/8 waves = 48.8/CU -> 100%
// ceiling), gather loop = exact k_gath1 structure (uniform d, 4 slots x
// 16-lane chunks of ONE node, butterfly), GEMM split across all 4 waves.

constexpr int NN = 100000;   // nodes
constexpr int NE = 1600000;  // edges
constexpr int BSH = 7;       // 128 nodes per bucket
constexpr int NB = (NN + 127) >> BSH;  // 782 buckets
constexpr int NBLK = 256;    // binning blocks
constexpr int EPB = NE / NBLK;  // 6250 edges per block (exact)
constexpr int TSTR = 784;    // table row stride (ints)

typedef _Float16 f16x8 __attribute__((ext_vector_type(8)));
typedef float f32x4 __attribute__((ext_vector_type(4)));

// ------------- per-(block,bucket) histogram (LDS atomics only) ---------------
__global__ __launch_bounds__(256) void k_hist(const int* __restrict__ cols,
                                              int* __restrict__ table) {
  __shared__ int cnt[NB];
  for (int i = threadIdx.x; i < NB; i += 256) cnt[i] = 0;
  __syncthreads();
  int base = blockIdx.x * EPB;
  for (int i = threadIdx.x; i < EPB; i += 256)
    atomicAdd(&cnt[cols[base + i] >> BSH], 1);
  __syncthreads();
  for (int i = threadIdx.x; i < NB; i += 256)
    table[blockIdx.x * TSTR + i] = cnt[i];
}

// ------- scan table columns over blocks: startOff + bucket totals ------------
__global__ __launch_bounds__(256) void k_scanT(const int* __restrict__ table,
                                               int* __restrict__ startOff,
                                               int* __restrict__ btot) {
  __shared__ int s[256];
  int b = blockIdx.x, t = threadIdx.x;
  int v = table[t * TSTR + b];
  s[t] = v;
  __syncthreads();
  for (int off = 1; off < 256; off <<= 1) {
    int tmp = (t >= off) ? s[t - off] : 0;
    __syncthreads();
    s[t] += tmp;
    __syncthreads();
  }
  startOff[t * TSTR + b] = s[t] - v;
  if (t == 255) btot[b] = s[t];
}

// ------- exclusive scan of 782 bucket totals -> bucketBase (1 block) ---------
__global__ __launch_bounds__(256) void k_scanBkt(const int* __restrict__ btot,
                                                 int* __restrict__ bucketBase) {
  __shared__ int s[256];
  int t = threadIdx.x;
  int base = t * 4;
  int d0 = (base + 0 < NB) ? btot[base + 0] : 0;
  int d1 = (base + 1 < NB) ? btot[base + 1] : 0;
  int d2 = (base + 2 < NB) ? btot[base + 2] : 0;
  int d3 = (base + 3 < NB) ? btot[base + 3] : 0;
  int tsum = d0 + d1 + d2 + d3;
  s[t] = tsum;
  __syncthreads();
  for (int off = 1; off < 256; off <<= 1) {
    int tmp = (t >= off) ? s[t - off] : 0;
    __syncthreads();
    s[t] += tmp;
    __syncthreads();
  }
  int ex = s[t] - tsum;
  if (base + 0 < NB) bucketBase[base + 0] = ex;
  if (base + 1 < NB) bucketBase[base + 1] = ex + d0;
  if (base + 2 < NB) bucketBase[base + 2] = ex + d0 + d1;
  if (base + 3 < NB) bucketBase[base + 3] = ex + d0 + d1 + d2;
}

// ------- scatter edges into bucket-grouped array (LDS counters only) ---------
__global__ __launch_bounds__(256) void k_scat(const int* __restrict__ rows,
                                              const int* __restrict__ cols,
                                              const int* __restrict__ startOff,
                                              const int* __restrict__ bucketBase,
                                              unsigned* __restrict__ binned) {
  __shared__ int scnt[NB];
  int blk = blockIdx.x;
  for (int i = threadIdx.x; i < NB; i += 256)
    scnt[i] = bucketBase[i] + startOff[blk * TSTR + i];
  __syncthreads();
  int base = blk * EPB;
  for (int i = threadIdx.x; i < EPB; i += 256) {
    int c = cols[base + i];
    int r = rows[base + i];
    int pos = atomicAdd(&scnt[c >> BSH], 1);
    binned[pos] = ((unsigned)r << BSH) | (unsigned)(c & 127);
  }
}

// ------- per-bucket fill: deg/rowptr/dinv + node-grouped srcIdx + y ----------
// one block per bucket; block exclusively owns all its output ranges.
// also converts this bucket's x rows to y = half(x*dinv) (k_y fused).
__global__ __launch_bounds__(256) void k_fillb(const unsigned* __restrict__ binned,
                                               const int* __restrict__ bucketBase,
                                               const int* __restrict__ btot,
                                               int* __restrict__ rowptr,
                                               int* __restrict__ deg,
                                               float* __restrict__ dinv,
                                               int* __restrict__ srcIdx,
                                               const float4* __restrict__ x4,
                                               float2* __restrict__ y8) {
  __shared__ int cnt[128];
  __shared__ int sc[128];
  __shared__ int rp[128];
  __shared__ float sdv[128];
  int b = blockIdx.x;
  int nb0 = b << BSH;
  int nn = min(128, NN - nb0);
  int tid = threadIdx.x;
  if (tid < 128) cnt[tid] = 0;
  __syncthreads();
  int ebeg = bucketBase[b];
  int eend = ebeg + btot[b];
  // pass 1: local degree count
  for (int p = ebeg + tid; p < eend; p += 256)
    atomicAdd(&cnt[binned[p] & 127], 1);
  __syncthreads();
  // block scan of the 128 local degrees
  int v = (tid < 128) ? cnt[tid] : 0;
  if (tid < 128) sc[tid] = v;
  __syncthreads();
  for (int off = 1; off < 128; off <<= 1) {
    int tmp = (tid < 128 && tid >= off) ? sc[tid - off] : 0;
    __syncthreads();
    if (tid < 128) sc[tid] += tmp;
    __syncthreads();
  }
  if (tid < 128) {
    int ex = sc[tid] - v;
    rp[tid] = ebeg + ex;
    float dv = rsqrtf((float)v + 1.0f);
    sdv[tid] = dv;
    if (tid < nn) {
      rowptr[nb0 + tid] = ebeg + ex;
      deg[nb0 + tid] = v;
      dinv[nb0 + tid] = dv;
    }
    cnt[tid] = 0;
  }
  __syncthreads();
  // pass 2: scatter srcIdx (node-grouped, contiguous per bucket)
  for (int p = ebeg + tid; p < eend; p += 256) {
    unsigned pk = binned[p];
    int cl = pk & 127;
    int local = atomicAdd(&cnt[cl], 1);
    srcIdx[rp[cl] + local] = (int)(pk >> BSH);
  }
  // pass 3 (fused k_y): convert this bucket's x rows -> y = half(x*dinv)
  int tot = nn << 5;  // nn rows * 32 float4 each
  const float4* xb = x4 + ((size_t)nb0 << 5);
  float2* yb = y8 + ((size_t)nb0 << 5);
  for (int i = tid; i < tot; i += 256) {
    float s = sdv[i >> 5];
    float4 vv = xb[i];
    union { __half2 h[2]; float2 f; } u;
    u.h[0] = __floats2half2_rn(vv.x * s, vv.y * s);
    u.h[1] = __floats2half2_rn(vv.z * s, vv.w * s);
    yb[i] = u.f;
  }
}

// ------------- weight convert+transpose, both layers in one launch ----------
// W1 [128][128] -> Wt1 [128][128]^T, W2 [128][64] -> Wt2 [64][128]^T (f16)
__global__ __launch_bounds__(256) void k_wt(const float* __restrict__ W1,
                                            const float* __restrict__ W2,
                                            __half* __restrict__ Wt1,
                                            __half* __restrict__ Wt2) {
  int i = blockIdx.x * 256 + threadIdx.x;  // 96*256 = 24576 = 16384 + 8192
  if (i < 16384) {
    int k = i >> 7, n = i & 127;
    Wt1[n * 128 + k] = __float2half(W1[i]);
  } else {
    int j = i - 16384;
    int k = j >> 6, n = j & 63;
    Wt2[n * 128 + k] = __float2half(W2[j]);
  }
}

// ---- fused gather + GEMM1(+bias,relu) + GEMM2(+dinv) ------------------------
// block = 32 rows, 4 waves. Wave w gathers local rows [w*8, w*8+8) with the
// k_gath1 wave-uniform loop: whole wave on ONE node, 4 slots (quad) x 16-lane
// 256B row chunks, 2-deep unroll = 8 rows (2KB) in flight, butterfly combine.
// Then 3 barriers: GEMM1 (4 waves: rowhalf x colhalf) sA->sB, GEMM2 sB->sA,
// vectorized store. Grid = NN/32 = 3125 exactly.
// MFMA 16x16x32 f16, fp32 acc. C/D: lane reg i = C[(l>>4)*4+i][t*16+(l&15)].
__global__ __launch_bounds__(256, 8) void k_fused(
    const __half* __restrict__ y, const int* __restrict__ rowptr,
    const int* __restrict__ deg, const int* __restrict__ srcIdx,
    const float* __restrict__ dinv, const __half* __restrict__ Wt1,
    const float* __restrict__ b1, const __half* __restrict__ Wt2,
    __half* __restrict__ z) {
  __shared__ __align__(16) __half sA[32][136];  // aggX tile -> z staging
  __shared__ __align__(16) __half sB[32][136];  // h1 tile
  const int w = threadIdx.x >> 6, l = threadIdx.x & 63;
  const int blk0 = blockIdx.x * 32;
  const int quad = l >> 4, m = l & 15;  // slot / 16B row chunk

  // ---------------- gather: wave w -> local rows [w*8, w*8+8) --------------
  for (int i = 0; i < 8; ++i) {
    const int lr = w * 8 + i;
    const int node = blk0 + lr;            // wave-uniform
    const int d = deg[node];
    const int ptr = rowptr[node];
    float acc[8];
#pragma unroll
    for (int j = 0; j < 8; j++) acc[j] = 0.0f;
    for (int base = 0; base < d; base += 64) {
      int cnt = min(64, d - base);
      int my = (l < cnt) ? srcIdx[ptr + base + l] : 0;
      int k = 0;
      for (; k + 8 <= cnt; k += 8) {       // 8 neighbors, 2 loads in flight
        int s0 = __shfl(my, k + quad);
        int s1 = __shfl(my, k + 4 + quad);
        f16x8 v0 = *reinterpret_cast<const f16x8*>(y + (size_t)s0 * 128 + m * 8);
        f16x8 v1 = *reinterpret_cast<const f16x8*>(y + (size_t)s1 * 128 + m * 8);
#pragma unroll
        for (int j = 0; j < 8; j++) acc[j] += (float)v0[j];
#pragma unroll
        for (int j = 0; j < 8; j++) acc[j] += (float)v1[j];
      }
      for (; k < cnt; k += 4) {            // remainder, predicated
        int idx = k + quad;
        bool valid = idx < cnt;
        int s0 = __shfl(my, valid ? idx : 0);
        f16x8 v0 = *reinterpret_cast<const f16x8*>(y + (size_t)s0 * 128 + m * 8);
        if (valid) {
#pragma unroll
          for (int j = 0; j < 8; j++) acc[j] += (float)v0[j];
        }
      }
    }
    // combine the 4 slots (same columns in all slots)
#pragma unroll
    for (int j = 0; j < 8; j++) acc[j] += __shfl_xor(acc[j], 16);
#pragma unroll
    for (int j = 0; j < 8; j++) acc[j] += __shfl_xor(acc[j], 32);
    if (quad == 0) {
      f16x8 sv = *reinterpret_cast<const f16x8*>(y + (size_t)node * 128 + m * 8);
      float scn = dinv[node];
      f16x8 o;
#pragma unroll
      for (int j = 0; j < 8; j++)
        o[j] = (_Float16)((acc[j] + (float)sv[j]) * scn);
      *reinterpret_cast<f16x8*>(&sA[lr][m * 8]) = o;
    }
  }
  __syncthreads();

  // ---------------- GEMM1: h1 = relu(aggX @ W1 + b1) ----------------
  // wave w: rows rt..rt+15 (rt = (w>>1)*16), col tiles ct..ct+3 (ct=(w&1)*4)
  const int rt = (w >> 1) * 16;
  const int ct = (w & 1) * 4;
  f16x8 afrag[4];
#pragma unroll
  for (int kk = 0; kk < 4; kk++)
    afrag[kk] = *reinterpret_cast<const f16x8*>(&sA[rt + m][kk * 32 + quad * 8]);
  f32x4 acc1[4];
#pragma unroll
  for (int t = 0; t < 4; t++) {
    float bv = b1[(ct + t) * 16 + m];
    acc1[t] = (f32x4){bv, bv, bv, bv};
  }
#pragma unroll
  for (int kk = 0; kk < 4; kk++) {
#pragma unroll
    for (int t = 0; t < 4; t++) {
      f16x8 b = *reinterpret_cast<const f16x8*>(
          Wt1 + (size_t)((ct + t) * 16 + m) * 128 + kk * 32 + quad * 8);
      acc1[t] = __builtin_amdgcn_mfma_f32_16x16x32_f16(afrag[kk], b, acc1[t], 0, 0, 0);
    }
  }
#pragma unroll
  for (int t = 0; t < 4; t++)
#pragma unroll
    for (int i = 0; i < 4; i++)
      sB[rt + quad * 4 + i][(ct + t) * 16 + m] =
          __float2half(fmaxf(acc1[t][i], 0.0f));
  __syncthreads();  // sB ready; also: all sA reads done -> sA reusable

  // ---------------- GEMM2: z = (h1 @ W2) * dinv[row] ----------------
  // wave w: rows rt..rt+15, col tiles c2..c2+1 (c2 = (w&1)*2 of 4)
  const int c2 = (w & 1) * 2;
  f16x8 hfrag[4];
#pragma unroll
  for (int kk = 0; kk < 4; kk++)
    hfrag[kk] = *reinterpret_cast<const f16x8*>(&sB[rt + m][kk * 32 + quad * 8]);
  f32x4 acc2[2];
#pragma unroll
  for (int t = 0; t < 2; t++) acc2[t] = (f32x4){0.f, 0.f, 0.f, 0.f};
#pragma unroll
  for (int kk = 0; kk < 4; kk++) {
#pragma unroll
    for (int t = 0; t < 2; t++) {
      f16x8 b = *reinterpret_cast<const f16x8*>(
          Wt2 + (size_t)((c2 + t) * 16 + m) * 128 + kk * 32 + quad * 8);
      acc2[t] = __builtin_amdgcn_mfma_f32_16x16x32_f16(hfrag[kk], b, acc2[t], 0, 0, 0);
    }
  }
  float rs[4];
#pragma unroll
  for (int i = 0; i < 4; i++) rs[i] = dinv[blk0 + rt + quad * 4 + i];
#pragma unroll
  for (int t = 0; t < 2; t++)
#pragma unroll
    for (int i = 0; i < 4; i++)
      sA[rt + quad * 4 + i][(c2 + t) * 16 + m] = __float2half(acc2[t][i] * rs[i]);
  __syncthreads();

  // vectorized store: 32 rows x 64 halves (128B/row), 1 float4 per thread
  {
    int r = threadIdx.x >> 3, cc = threadIdx.x & 7;
    *reinterpret_cast<float4*>(z + (size_t)(blk0 + r) * 64 + cc * 8) =
        *reinterpret_cast<const float4*>(&sA[r][cc * 8]);
  }
}

// ---------------- gather-aggregate, width 64 half (wave per node) ------------
// 16B/lane: 8 lanes cover one 128B source row -> 8 neighbor rows per load
// instruction, 2-deep unroll = 16 rows in flight. Butterfly xor 8/16/32.
__global__ __launch_bounds__(256) void k_gath2(const __half* __restrict__ z,
                                               const int* __restrict__ rowptr,
                                               const int* __restrict__ deg,
                                               const int* __restrict__ srcIdx,
                                               const float* __restrict__ dinv,
                                               const float* __restrict__ b2,
                                               float* __restrict__ out) {
  int node = blockIdx.x * 4 + (threadIdx.x >> 6);
  if (node >= NN) return;
  int lane = threadIdx.x & 63;
  int g = lane >> 3;       // neighbor slot 0..7
  int c = lane & 7;        // column chunk: halfs [c*8, c*8+8)
  int d = deg[node];
  int p = rowptr[node];
  size_t coff = (size_t)c * 8;
  float acc[8];
#pragma unroll
  for (int i = 0; i < 8; i++) acc[i] = 0.0f;

  for (int base = 0; base < d; base += 64) {
    int cnt = min(64, d - base);
    int my = (lane < cnt) ? srcIdx[p + base + lane] : 0;
    int k = 0;
    for (; k + 16 <= cnt; k += 16) {         // 16 neighbors, 2 loads in flight
      int s0 = __shfl(my, k + g);
      int s1 = __shfl(my, k + 8 + g);
      f16x8 v0 = *reinterpret_cast<const f16x8*>(z + (size_t)s0 * 64 + coff);
      f16x8 v1 = *reinterpret_cast<const f16x8*>(z + (size_t)s1 * 64 + coff);
#pragma unroll
      for (int i = 0; i < 8; i++) acc[i] += (float)v0[i];
#pragma unroll
      for (int i = 0; i < 8; i++) acc[i] += (float)v1[i];
    }
    for (; k < cnt; k += 8) {                // remainder, predicated
      int idx = k + g;
      bool valid = idx < cnt;
      int s0 = __shfl(my, valid ? idx : 0);
      f16x8 v0 = *reinterpret_cast<const f16x8*>(z + (size_t)s0 * 64 + coff);
      if (valid) {
#pragma unroll
        for (int i = 0; i < 8; i++) acc[i] += (float)v0[i];
      }
    }
  }
#pragma unroll
  for (int i = 0; i < 8; i++) acc[i] += __shfl_xor(acc[i], 8);
#pragma unroll
  for (int i = 0; i < 8; i++) acc[i] += __shfl_xor(acc[i], 16);
#pragma unroll
  for (int i = 0; i < 8; i++) acc[i] += __shfl_xor(acc[i], 32);
  if (g == 0) {
    f16x8 sv = *reinterpret_cast<const f16x8*>(z + (size_t)node * 64 + coff);
    float s = dinv[node];
    const float4* b4 = reinterpret_cast<const float4*>(b2);
    float4 bv0 = b4[2 * c], bv1 = b4[2 * c + 1];
    float4 o0, o1;
    o0.x = (acc[0] + (float)sv[0]) * s + bv0.x;
    o0.y = (acc[1] + (float)sv[1]) * s + bv0.y;
    o0.z = (acc[2] + (float)sv[2]) * s + bv0.z;
    o0.w = (acc[3] + (float)sv[3]) * s + bv0.w;
    o1.x = (acc[4] + (float)sv[4]) * s + bv1.x;
    o1.y = (acc[5] + (float)sv[5]) * s + bv1.y;
    o1.z = (acc[6] + (float)sv[6]) * s + bv1.z;
    o1.w = (acc[7] + (float)sv[7]) * s + bv1.w;
    float4* op = reinterpret_cast<float4*>(out + (size_t)node * 64 + coff);
    op[0] = o0;
    op[1] = o1;
  }
}

extern "C" void kernel_launch(void* const* d_in, const int* in_sizes, int n_in,
                              void* d_out, int out_size, void* d_ws, size_t ws_size,
                              hipStream_t stream) {
  const float* x  = (const float*)d_in[0];
  const int*   ei = (const int*)d_in[1];  // [2, NE] row-major
  const int* rows = ei;
  const int* cols = ei + NE;
  const float* W1 = (const float*)d_in[3];
  const float* b1 = (const float*)d_in[4];
  const float* W2 = (const float*)d_in[5];
  const float* b2 = (const float*)d_in[6];
  float* out = (float*)d_out;

  // ---- workspace carve (~60 MB) ----
  char* base = (char*)d_ws;
  constexpr size_t MB = 1 << 20;
  int*      deg       = (int*)(base + 0 * MB);
  int*      rowptr    = (int*)(base + 1 * MB);
  float*    dinv      = (float*)(base + 2 * MB);
  int*      btot      = (int*)(base + 3 * MB);                  // 3.2 KB
  int*      bucketBase= (int*)(base + 3 * MB + 16 * 1024);      // 3.2 KB
  __half*   Wt1       = (__half*)(base + 3 * MB + 64 * 1024);   // 32 KB
  __half*   Wt2       = (__half*)(base + 3 * MB + 128 * 1024);  // 16 KB
  int*      table     = (int*)(base + 4 * MB);   // 803 KB
  int*      startOff  = (int*)(base + 5 * MB);   // 803 KB
  unsigned* binned    = (unsigned*)(base + 6 * MB);   // 6.4 MB
  int*      srcIdx    = (int*)(base + 13 * MB);       // 6.4 MB
  __half*   y         = (__half*)(base + 20 * MB);    // 25.6 MB
  __half*   z         = (__half*)(base + 46 * MB);    // 12.8 MB (y stays live!)

  k_wt<<<96, 256, 0, stream>>>(W1, W2, Wt1, Wt2);
  k_hist<<<NBLK, 256, 0, stream>>>(cols, table);
  k_scanT<<<NB, 256, 0, stream>>>(table, startOff, btot);
  k_scanBkt<<<1, 256, 0, stream>>>(btot, bucketBase);
  k_scat<<<NBLK, 256, 0, stream>>>(rows, cols, startOff, bucketBase, binned);
  k_fillb<<<NB, 256, 0, stream>>>(binned, bucketBase, btot, rowptr, deg, dinv,
                                  srcIdx, (const float4*)x, (float2*)y);
  k_fused<<<NN / 32, 256, 0, stream>>>(y, rowptr, deg, srcIdx, dinv,
                                       Wt1, b1, Wt2, z);
  k_gath2<<<(NN + 3) / 4, 256, 0, stream>>>(z, rowptr, deg, srcIdx, dinv, b2, out);
}